// Round 9
// baseline (147.310 us; speedup 1.0000x reference)
//
#include <hip/hip_runtime.h>

#define CC 64      // channels
#define SS 16384   // D*W*H
#define NN 65536   // B*S tokens
#define KK 2048    // codebook size
#define BM 64      // tokens per block tile (conv/finish)
#define BMA 128    // tokens per argmin block

typedef __attribute__((ext_vector_type(8))) short bf16x8_t;
typedef __attribute__((ext_vector_type(4))) float fx4_t;
#define MFMA16 __builtin_amdgcn_mfma_f32_16x16x32_bf16

__device__ __forceinline__ unsigned short f2bf(float f) {
  unsigned u = __builtin_bit_cast(unsigned, f);
  return (unsigned short)((u + 0x7fff + ((u >> 16) & 1)) >> 16);  // RNE
}
__device__ __forceinline__ float bf2f(unsigned short h) {
  unsigned u = (unsigned)h << 16;
  return __builtin_bit_cast(float, u);
}
__device__ __forceinline__ void glds16(const void* g, void* l) {
  __builtin_amdgcn_global_load_lds(
      (const __attribute__((address_space(1))) unsigned*)g,
      (__attribute__((address_space(3))) unsigned*)l, 16, 0, 0);
}

// ======= kernel 1: pre = W_in@x + b_in (fp64) + emit bf16-split xh/xl ====
// xf fp32 correctly-rounded (channel-major, for fp64 rerank + finish);
// xh/xl bf16 token-major [tok][64] (for argmin A-frags, read from global).
__global__ __launch_bounds__(256, 4) void vq_conv_in(
    const float* __restrict__ x, const float* __restrict__ w_in,
    const float* __restrict__ b_in, float* __restrict__ xf,
    unsigned short* __restrict__ xh, unsigned short* __restrict__ xl) {
  __shared__ float xs[CC][BM];
  __shared__ float wt[CC][CC];
  int t = threadIdx.x;
  int n0 = blockIdx.x * BM;
  int b = n0 >> 14, s0 = n0 & (SS - 1);
  {
    int o = t >> 2, c0 = (t & 3) * 16;
    const float4* wr = (const float4*)(w_in + o * CC + c0);
#pragma unroll
    for (int i = 0; i < 4; ++i) {
      float4 v = wr[i];
      int ci = c0 + 4 * i;
      wt[ci + 0][o] = v.x; wt[ci + 1][o] = v.y;
      wt[ci + 2][o] = v.z; wt[ci + 3][o] = v.w;
    }
  }
#pragma unroll
  for (int i = 0; i < 4; ++i) {
    int e4 = t + 256 * i;
    int ci = e4 >> 4, tok4 = (e4 & 15) * 4;
    *(float4*)&xs[ci][tok4] =
        *(const float4*)(x + (size_t)b * CC * SS + (size_t)ci * SS + s0 + tok4);
  }
  __syncthreads();
  int tx = t & 15, ty = t >> 4;
  double acc[4][4];
#pragma unroll
  for (int j = 0; j < 4; ++j) {
    double bj = (double)b_in[tx * 4 + j];
#pragma unroll
    for (int m = 0; m < 4; ++m) acc[m][j] = bj;
  }
#pragma unroll 8
  for (int ci = 0; ci < CC; ++ci) {
    float4 xq = *(const float4*)&xs[ci][ty * 4];
    float4 wq = *(const float4*)&wt[ci][tx * 4];
    double xm[4] = {xq.x, xq.y, xq.z, xq.w};
    double wm[4] = {wq.x, wq.y, wq.z, wq.w};
#pragma unroll
    for (int m = 0; m < 4; ++m)
#pragma unroll
      for (int j = 0; j < 4; ++j) acc[m][j] = fma(xm[m], wm[j], acc[m][j]);
  }
#pragma unroll
  for (int j = 0; j < 4; ++j) {
    float4 ov = make_float4((float)acc[0][j], (float)acc[1][j],
                            (float)acc[2][j], (float)acc[3][j]);
    *(float4*)(xf + (size_t)b * CC * SS + (size_t)(tx * 4 + j) * SS + s0 +
               ty * 4) = ov;
  }
  // emit bf16 hi/lo, token-major: xh[tok*64 + tx*4 + j]
#pragma unroll
  for (int m = 0; m < 4; ++m) {
    size_t tok = (size_t)n0 + ty * 4 + m;
    unsigned short h[4], l[4];
#pragma unroll
    for (int j = 0; j < 4; ++j) {
      float v = (float)acc[m][j];
      h[j] = f2bf(v);
      l[j] = f2bf(v - bf2f(h[j]));
    }
    uint2 wh = make_uint2((unsigned)h[0] | ((unsigned)h[1] << 16),
                          (unsigned)h[2] | ((unsigned)h[3] << 16));
    uint2 wl = make_uint2((unsigned)l[0] | ((unsigned)l[1] << 16),
                          (unsigned)l[2] | ((unsigned)l[3] << 16));
    *(uint2*)(xh + tok * CC + tx * 4) = wh;
    *(uint2*)(xl + tok * CC + tx * 4) = wl;
  }
}

// ===== kernel 2: split codebook to bf16 hi/lo + ch = -0.5*||c||^2 =======
__global__ __launch_bounds__(256) void vq_split(
    const float* __restrict__ cb, unsigned short* __restrict__ cbh,
    unsigned short* __restrict__ cbl, float* __restrict__ ch) {
  int k = blockIdx.x * 256 + threadIdx.x;
  const float4* r = (const float4*)(cb + (size_t)k * CC);
  unsigned* oh = (unsigned*)(cbh + (size_t)k * CC);
  unsigned* ol = (unsigned*)(cbl + (size_t)k * CC);
  float s = 0.f;
#pragma unroll
  for (int i = 0; i < 16; ++i) {
    float4 v = r[i];
    float vv[4] = {v.x, v.y, v.z, v.w};
    unsigned short h[4], l[4];
#pragma unroll
    for (int u = 0; u < 4; ++u) {
      s = fmaf(vv[u], vv[u], s);
      h[u] = f2bf(vv[u]);
      l[u] = f2bf(vv[u] - bf2f(h[u]));
    }
    oh[2 * i + 0] = (unsigned)h[0] | ((unsigned)h[1] << 16);
    oh[2 * i + 1] = (unsigned)h[2] | ((unsigned)h[3] << 16);
    ol[2 * i + 0] = (unsigned)l[0] | ((unsigned)l[1] << 16);
    ol[2 * i + 1] = (unsigned)l[2] | ((unsigned)l[3] << 16);
  }
  ch[k] = -0.5f * s;
}

// ====== kernel 3: MFMA scan, K-split x4, top-2 per quarter ==============
// blockIdx bits[1:0] = K-quarter (512 codes, 8 tiles of 64); rest = 128-token
// group. A-frags loaded directly from global xh/xl (token-major, coalesced).
// B tiles double-buffered via glds w/ inverse-swizzled source; cn staged to
// LDS once. All inner-loop addresses hoisted -> ds_read immediate offsets.
// 3 MFMA passes (hh+hl+lh); top-2 per quarter -> 8 cands, fp64 rerank after.
__global__ __launch_bounds__(256, 4) void vq_mfma_argmin(
    const unsigned short* __restrict__ xh, const unsigned short* __restrict__ xl,
    const unsigned char* __restrict__ cbh, const unsigned char* __restrict__ cbl,
    const float* __restrict__ ch, int* __restrict__ cidx) {
  __shared__ __align__(16) unsigned char smem[34816];  // 32K B-dbuf + 2K cn
  int t = threadIdx.x;
  int q = blockIdx.x & 3;
  int n0 = (blockIdx.x >> 2) * BMA;
  int lane = t & 63, w = t >> 6;
  int col = lane & 15, quad = lane >> 4;
  // ---- A-frags direct from global (tok*128B; kk*64 + quad*16 within) ----
  bf16x8_t ah[2][2], al[2][2];
#pragma unroll
  for (int rt = 0; rt < 2; ++rt)
#pragma unroll
    for (int kk = 0; kk < 2; ++kk) {
      size_t byo = ((size_t)n0 + w * 32 + rt * 16 + col) * 128 + kk * 64 +
                   quad * 16;
      ah[rt][kk] = *(const bf16x8_t*)((const unsigned char*)xh + byo);
      al[rt][kk] = *(const bf16x8_t*)((const unsigned char*)xl + byo);
    }
  // ---- stage cn (2KB) + B tile 0 ----
  const unsigned char* ghh = cbh + (size_t)q * 65536;
  const unsigned char* glh = cbl + (size_t)q * 65536;
  int srcoff = (lane * 16) ^ (((lane >> 3) & 7) << 4);  // inverse swizzle
  if (w < 2)
    glds16((const unsigned char*)ch + q * 2048 + w * 1024 + lane * 16,
           smem + 32768 + w * 1024);
  glds16(ghh + w * 2048 + srcoff, smem + w * 2048);
  glds16(ghh + w * 2048 + 1024 + srcoff, smem + w * 2048 + 1024);
  glds16(glh + w * 2048 + srcoff, smem + 8192 + w * 2048);
  glds16(glh + w * 2048 + 1024 + srcoff, smem + 8192 + w * 2048 + 1024);
  __syncthreads();
  float best[2][4], secd[2][4];
  int bi[2][4], si[2][4];
#pragma unroll
  for (int rt = 0; rt < 2; ++rt)
#pragma unroll
    for (int r = 0; r < 4; ++r) {
      best[rt][r] = -3.402823466e+38f; secd[rt][r] = -3.402823466e+38f;
      bi[rt][r] = 0; si[rt][r] = 0;
    }
  // hoisted per-thread B read bases (sub -> +2048*sub immediate)
  int swz = (col & 7) << 4;
  int cb0 = col * 128 + ((quad * 16) ^ swz);
  int cb1 = col * 128 + ((64 + quad * 16) ^ swz);
  int kcol = q * 512 + col;
  const int NT = 8;
  for (int kt = 0; kt < NT; ++kt) {
    unsigned char* bufc = smem + (kt & 1) * 16384;
    unsigned char* bufn = smem + ((kt + 1) & 1) * 16384;
    if (kt + 1 < NT) {
      size_t gof = (size_t)(kt + 1) * 8192 + w * 2048 + srcoff;
      glds16(ghh + gof, bufn + w * 2048);
      glds16(ghh + gof + 1024, bufn + w * 2048 + 1024);
      glds16(glh + gof, bufn + 8192 + w * 2048);
      glds16(glh + gof + 1024, bufn + 8192 + w * 2048 + 1024);
    }
    const unsigned char* cnb = smem + 32768 + kt * 256 + col * 4;
    int kbt = kcol + kt * 64;
#pragma unroll
    for (int sub = 0; sub < 4; ++sub) {
      bf16x8_t bh0 = *(const bf16x8_t*)(bufc + cb0 + 2048 * sub);
      bf16x8_t bh1 = *(const bf16x8_t*)(bufc + cb1 + 2048 * sub);
      bf16x8_t bl0 = *(const bf16x8_t*)(bufc + 8192 + cb0 + 2048 * sub);
      bf16x8_t bl1 = *(const bf16x8_t*)(bufc + 8192 + cb1 + 2048 * sub);
      float cn = *(const float*)(cnb + 64 * sub);
      int kbase = kbt + sub * 16;
#pragma unroll
      for (int rt = 0; rt < 2; ++rt) {
        fx4_t acc = {cn, cn, cn, cn};
        acc = MFMA16(al[rt][0], bh0, acc, 0, 0, 0);  // lh
        acc = MFMA16(al[rt][1], bh1, acc, 0, 0, 0);
        acc = MFMA16(ah[rt][0], bl0, acc, 0, 0, 0);  // hl
        acc = MFMA16(ah[rt][1], bl1, acc, 0, 0, 0);
        acc = MFMA16(ah[rt][0], bh0, acc, 0, 0, 0);  // hh
        acc = MFMA16(ah[rt][1], bh1, acc, 0, 0, 0);
#pragma unroll
        for (int r = 0; r < 4; ++r) {
          float v = acc[r];
          if (v > best[rt][r]) {
            secd[rt][r] = best[rt][r]; si[rt][r] = bi[rt][r];
            best[rt][r] = v; bi[rt][r] = kbase;
          } else if (v > secd[rt][r]) {
            secd[rt][r] = v; si[rt][r] = kbase;
          }
        }
      }
    }
    __syncthreads();
  }
  // cross-lane merge over 16 cols per token row (lex: max S, min k)
#pragma unroll
  for (int step = 1; step <= 8; step <<= 1) {
#pragma unroll
    for (int rt = 0; rt < 2; ++rt)
#pragma unroll
      for (int r = 0; r < 4; ++r) {
        float ob = __shfl_xor(best[rt][r], step, 64);
        int oi = __shfl_xor(bi[rt][r], step, 64);
        float os = __shfl_xor(secd[rt][r], step, 64);
        int oj = __shfl_xor(si[rt][r], step, 64);
        bool oW = (ob > best[rt][r]) || (ob == best[rt][r] && oi < bi[rt][r]);
        float nb = oW ? ob : best[rt][r];
        int ni = oW ? oi : bi[rt][r];
        float lb = oW ? best[rt][r] : ob;
        int li = oW ? bi[rt][r] : oi;
        float ws = oW ? os : secd[rt][r];
        int wi = oW ? oj : si[rt][r];
        bool sW = (ws > lb) || (ws == lb && wi < li);
        best[rt][r] = nb; bi[rt][r] = ni;
        secd[rt][r] = sW ? ws : lb; si[rt][r] = sW ? wi : li;
      }
  }
  if (col == 0) {
#pragma unroll
    for (int rt = 0; rt < 2; ++rt)
#pragma unroll
      for (int r = 0; r < 4; ++r) {
        int token = n0 + w * 32 + rt * 16 + quad * 4 + r;
        cidx[(size_t)(2 * q + 0) * NN + token] = bi[rt][r];
        cidx[(size_t)(2 * q + 1) * NN + token] = si[rt][r];
      }
  }
}

// ============ kernel 4: exact fp64 select among 8 candidates ============
__global__ __launch_bounds__(256) void vq_select(
    const float* __restrict__ xf, const float* __restrict__ cb,
    const int* __restrict__ cidx, int* __restrict__ sel) {
  int t = threadIdx.x;
  int n = blockIdx.x * 32 + (t >> 3);
  int cand = t & 7;
  int b = n >> 14, s = n & (SS - 1);
  int kj = cidx[(size_t)cand * NN + n];
  const float* xp = xf + (size_t)b * CC * SS + s;
  const float* cp = cb + (size_t)kj * CC;
  double dj = 0.0;
#pragma unroll 8
  for (int c = 0; c < CC; ++c) {
    double df = (double)xp[(size_t)c * SS] - (double)cp[c];
    dj = fma(df, df, dj);
  }
#pragma unroll
  for (int step = 1; step <= 4; step <<= 1) {
    double od = __shfl_xor(dj, step, 64);
    int ok = __shfl_xor(kj, step, 64);
    if (od < dj || (od == dj && ok < kj)) { dj = od; kj = ok; }
  }
  if (cand == 0) sel[n] = kj;
}

// ====== kernel 5: gather q, z-write, losses, conv_out (4x4 tile) ======
__global__ __launch_bounds__(256, 3) void vq_finish(
    const float* __restrict__ cb, const float* __restrict__ w_out,
    const float* __restrict__ b_out, const int* __restrict__ sel,
    float* __restrict__ dout, float* __restrict__ loss_acc) {
  __shared__ float qs[CC][BM];
  __shared__ float xs[CC][BM];
  __shared__ float wt[CC][CC];
  __shared__ int ids[BM];
  int t = threadIdx.x;
  int n0 = blockIdx.x * BM;
  int b = n0 >> 14, s0 = n0 & (SS - 1);
  float* zreg = dout + (size_t)NN * CC;
  if (t < BM) ids[t] = sel[n0 + t];
  {
    int o = t >> 2, c0 = (t & 3) * 16;
    const float4* wr = (const float4*)(w_out + o * CC + c0);
#pragma unroll
    for (int i = 0; i < 4; ++i) {
      float4 v = wr[i];
      int ci = c0 + 4 * i;
      wt[ci + 0][o] = v.x; wt[ci + 1][o] = v.y;
      wt[ci + 2][o] = v.z; wt[ci + 3][o] = v.w;
    }
  }
#pragma unroll
  for (int i = 0; i < 4; ++i) {
    int e4 = t + 256 * i;
    int ci = e4 >> 4, tok4 = (e4 & 15) * 4;
    *(float4*)&xs[ci][tok4] = *(const float4*)(zreg + (size_t)b * CC * SS +
                                               (size_t)ci * SS + s0 + tok4);
  }
  __syncthreads();
  {
    int tok = t >> 2, c0 = (t & 3) * 16;
    const float4* qr = (const float4*)(cb + (size_t)ids[tok] * CC + c0);
#pragma unroll
    for (int i = 0; i < 4; ++i) {
      float4 v = qr[i];
      int ch = c0 + 4 * i;
      qs[ch + 0][tok] = v.x; qs[ch + 1][tok] = v.y;
      qs[ch + 2][tok] = v.z; qs[ch + 3][tok] = v.w;
    }
  }
  __syncthreads();
  float lsum = 0.f;
#pragma unroll
  for (int i = 0; i < 4; ++i) {
    int e4 = t + 256 * i;
    int ci = e4 >> 4, tok4 = (e4 & 15) * 4;
    float4 qv = *(const float4*)&qs[ci][tok4];
    float4 xv = *(const float4*)&xs[ci][tok4];
    float dx = qv.x - xv.x, dy = qv.y - xv.y;
    float dz = qv.z - xv.z, dw = qv.w - xv.w;
    lsum = fmaf(dx, dx, lsum); lsum = fmaf(dy, dy, lsum);
    lsum = fmaf(dz, dz, lsum); lsum = fmaf(dw, dw, lsum);
    *(float4*)(zreg + (size_t)b * CC * SS + (size_t)ci * SS + s0 + tok4) = qv;
  }
  int tx = t & 15, ty = t >> 4;
  float acc[4][4];
#pragma unroll
  for (int j = 0; j < 4; ++j) {
    float bj = b_out[tx * 4 + j];
#pragma unroll
    for (int m = 0; m < 4; ++m) acc[m][j] = bj;
  }
#pragma unroll 8
  for (int ci = 0; ci < CC; ++ci) {
    float4 xq = *(const float4*)&qs[ci][ty * 4];
    float4 wq = *(const float4*)&wt[ci][tx * 4];
    float xm[4] = {xq.x, xq.y, xq.z, xq.w};
    float wm[4] = {wq.x, wq.y, wq.z, wq.w};
#pragma unroll
    for (int m = 0; m < 4; ++m)
#pragma unroll
      for (int j = 0; j < 4; ++j) acc[m][j] = fmaf(xm[m], wm[j], acc[m][j]);
  }
#pragma unroll
  for (int j = 0; j < 4; ++j) {
    float4 ov = make_float4(acc[0][j], acc[1][j], acc[2][j], acc[3][j]);
    *(float4*)(dout + (size_t)b * CC * SS + (size_t)(tx * 4 + j) * SS + s0 +
               ty * 4) = ov;
  }
#pragma unroll
  for (int off = 32; off > 0; off >>= 1) lsum += __shfl_down(lsum, off, 64);
  __shared__ float wsum[4];
  if ((t & 63) == 0) wsum[t >> 6] = lsum;
  __syncthreads();
  if (t == 0) atomicAdd(loss_acc, wsum[0] + wsum[1] + wsum[2] + wsum[3]);
}

// ============ kernel 6: finalize scalar losses ============
__global__ void vq_finalize(const float* __restrict__ loss_acc,
                            float* __restrict__ dout) {
  float l = loss_acc[0] * (1.0f / (float)((size_t)NN * CC));
  dout[(size_t)2 * NN * CC + 0] = l;  // codebook_loss
  dout[(size_t)2 * NN * CC + 1] = l;  // commitment_loss
}

extern "C" void kernel_launch(void* const* d_in, const int* in_sizes, int n_in,
                              void* d_out, int out_size, void* d_ws,
                              size_t ws_size, hipStream_t stream) {
  const float* x = (const float*)d_in[0];
  const float* cb = (const float*)d_in[1];
  const float* w_in = (const float*)d_in[2];
  const float* b_in = (const float*)d_in[3];
  const float* w_out = (const float*)d_in[4];
  const float* b_out = (const float*)d_in[5];
  float* out = (float*)d_out;
  float* zreg = out + (size_t)NN * CC;  // z region doubles as xf scratch
  // out region doubles as xh/xl scratch (16.77MB, overwritten by finish)
  unsigned short* xh = (unsigned short*)out;
  unsigned short* xl = xh + (size_t)NN * CC;

  // ws: [0,4) loss; [1024,9216) ch; [16K,272K) cbh; [272K,528K) cbl;
  //     [528K..] cidx (8 planes x NN) then sel. ~2.9 MB total.
  float* loss_acc = (float*)d_ws;
  float* ch = (float*)((char*)d_ws + 1024);
  unsigned short* cbh = (unsigned short*)((char*)d_ws + 16384);
  unsigned short* cbl = (unsigned short*)((char*)d_ws + 16384 + 262144);
  int* cidx = (int*)((char*)d_ws + 16384 + 2 * 262144);
  int* sel = (int*)((char*)d_ws + 16384 + 2 * 262144 + 8 * NN * 4);

  hipMemsetAsync(d_ws, 0, 4, stream);

  vq_conv_in<<<NN / BM, 256, 0, stream>>>(x, w_in, b_in, zreg, xh, xl);
  vq_split<<<KK / 256, 256, 0, stream>>>(cb, cbh, cbl, ch);
  vq_mfma_argmin<<<(NN / BMA) * 4, 256, 0, stream>>>(
      xh, xl, (const unsigned char*)cbh, (const unsigned char*)cbl, ch, cidx);
  vq_select<<<NN / 32, 256, 0, stream>>>(zreg, cb, cidx, sel);
  vq_finish<<<NN / BM, 256, 0, stream>>>(cb, w_out, b_out, sel, out, loss_acc);
  vq_finalize<<<1, 1, 0, stream>>>(loss_acc, out);
}

// Round 10
// 145.969 us; speedup vs baseline: 1.0092x; 1.0092x over previous
//
#include <hip/hip_runtime.h>

#define CC 64      // channels
#define SS 16384   // D*W*H
#define NN 65536   // B*S tokens
#define KK 2048    // codebook size
#define BM 64      // tokens per block tile (conv/finish)
#define BMA 128    // tokens per argmin block

typedef __attribute__((ext_vector_type(8))) short bf16x8_t;
typedef __attribute__((ext_vector_type(4))) float fx4_t;
#define MFMA16 __builtin_amdgcn_mfma_f32_16x16x32_bf16

__device__ __forceinline__ unsigned short f2bf(float f) {
  unsigned u = __builtin_bit_cast(unsigned, f);
  return (unsigned short)((u + 0x7fff + ((u >> 16) & 1)) >> 16);  // RNE
}
__device__ __forceinline__ float bf2f(unsigned short h) {
  unsigned u = (unsigned)h << 16;
  return __builtin_bit_cast(float, u);
}
__device__ __forceinline__ void glds16(const void* g, void* l) {
  __builtin_amdgcn_global_load_lds(
      (const __attribute__((address_space(1))) unsigned*)g,
      (__attribute__((address_space(3))) unsigned*)l, 16, 0, 0);
}

// ============ kernel 1: pre = W_in @ x + b_in (fp64 accum, 4x4 tile) =====
__global__ __launch_bounds__(256, 4) void vq_conv_in(
    const float* __restrict__ x, const float* __restrict__ w_in,
    const float* __restrict__ b_in, float* __restrict__ xf) {
  __shared__ float xs[CC][BM];
  __shared__ float wt[CC][CC];
  int t = threadIdx.x;
  int n0 = blockIdx.x * BM;
  int b = n0 >> 14, s0 = n0 & (SS - 1);
  {
    int o = t >> 2, c0 = (t & 3) * 16;
    const float4* wr = (const float4*)(w_in + o * CC + c0);
#pragma unroll
    for (int i = 0; i < 4; ++i) {
      float4 v = wr[i];
      int ci = c0 + 4 * i;
      wt[ci + 0][o] = v.x; wt[ci + 1][o] = v.y;
      wt[ci + 2][o] = v.z; wt[ci + 3][o] = v.w;
    }
  }
#pragma unroll
  for (int i = 0; i < 4; ++i) {
    int e4 = t + 256 * i;
    int ci = e4 >> 4, tok4 = (e4 & 15) * 4;
    *(float4*)&xs[ci][tok4] =
        *(const float4*)(x + (size_t)b * CC * SS + (size_t)ci * SS + s0 + tok4);
  }
  __syncthreads();
  int tx = t & 15, ty = t >> 4;
  double acc[4][4];
#pragma unroll
  for (int j = 0; j < 4; ++j) {
    double bj = (double)b_in[tx * 4 + j];
#pragma unroll
    for (int m = 0; m < 4; ++m) acc[m][j] = bj;
  }
#pragma unroll 8
  for (int ci = 0; ci < CC; ++ci) {
    float4 xq = *(const float4*)&xs[ci][ty * 4];
    float4 wq = *(const float4*)&wt[ci][tx * 4];
    double xm[4] = {xq.x, xq.y, xq.z, xq.w};
    double wm[4] = {wq.x, wq.y, wq.z, wq.w};
#pragma unroll
    for (int m = 0; m < 4; ++m)
#pragma unroll
      for (int j = 0; j < 4; ++j) acc[m][j] = fma(xm[m], wm[j], acc[m][j]);
  }
#pragma unroll
  for (int j = 0; j < 4; ++j) {
    float4 ov = make_float4((float)acc[0][j], (float)acc[1][j],
                            (float)acc[2][j], (float)acc[3][j]);
    *(float4*)(xf + (size_t)b * CC * SS + (size_t)(tx * 4 + j) * SS + s0 +
               ty * 4) = ov;
  }
}

// ===== kernel 2: split codebook to bf16 hi/lo + ch = -0.5*||c||^2 =======
__global__ __launch_bounds__(256) void vq_split(
    const float* __restrict__ cb, unsigned short* __restrict__ cbh,
    unsigned short* __restrict__ cbl, float* __restrict__ ch) {
  int k = blockIdx.x * 256 + threadIdx.x;
  const float4* r = (const float4*)(cb + (size_t)k * CC);
  unsigned* oh = (unsigned*)(cbh + (size_t)k * CC);
  unsigned* ol = (unsigned*)(cbl + (size_t)k * CC);
  float s = 0.f;
#pragma unroll
  for (int i = 0; i < 16; ++i) {
    float4 v = r[i];
    float vv[4] = {v.x, v.y, v.z, v.w};
    unsigned short h[4], l[4];
#pragma unroll
    for (int u = 0; u < 4; ++u) {
      s = fmaf(vv[u], vv[u], s);
      h[u] = f2bf(vv[u]);
      l[u] = f2bf(vv[u] - bf2f(h[u]));
    }
    oh[2 * i + 0] = (unsigned)h[0] | ((unsigned)h[1] << 16);
    oh[2 * i + 1] = (unsigned)h[2] | ((unsigned)h[3] << 16);
    ol[2 * i + 0] = (unsigned)l[0] | ((unsigned)l[1] << 16);
    ol[2 * i + 1] = (unsigned)l[2] | ((unsigned)l[3] << 16);
  }
  ch[k] = -0.5f * s;
}

// ====== kernel 3: MFMA scan (R8 base + hand pipeline + cn-in-LDS) =======
// blockIdx bit0 = K-half; 16 tiles of 64 codes, B double-buffered via glds
// (inverse-swizzled source). 2-deep named B-frag prefetch + split MFMA
// chains force ~100 VGPR live -> real pipelining (R8/R9 sat at 60 VGPR,
// zero prefetch depth). cn staged to LDS once, reg-prefetched per tile.
__global__ __launch_bounds__(256, 4) void vq_mfma_argmin(
    const float* __restrict__ xf, const unsigned char* __restrict__ cbh,
    const unsigned char* __restrict__ cbl, const float* __restrict__ ch,
    int* __restrict__ cidx) {
  __shared__ __align__(16) unsigned char smem[36864];  // 32K B-dbuf + 4K cn
  int t = threadIdx.x;
  int kh = blockIdx.x & 1;
  int n0 = (blockIdx.x >> 1) * BMA;
  int b = n0 >> 14, s0 = n0 & (SS - 1);
  // ---- phase A: stage x as bf16 hi/lo token-major, swizzled ----
  {
    int tok = t & 127;
    int half = t >> 7;
    const float* xb = xf + (size_t)b * CC * SS + s0 + tok;
#pragma unroll
    for (int i = 0; i < 4; ++i) {
      int c0 = half * 32 + i * 8;
      bf16x8_t h8, l8;
#pragma unroll
      for (int j = 0; j < 8; ++j) {
        float v = xb[(size_t)(c0 + j) * SS];
        unsigned short hs = f2bf(v);
        h8[j] = (short)hs;
        l8[j] = (short)f2bf(v - bf2f(hs));
      }
      int ad = tok * 128 + ((half * 64 + i * 16) ^ ((tok & 7) << 4));
      *(bf16x8_t*)(smem + ad) = h8;
      *(bf16x8_t*)(smem + 16384 + ad) = l8;
    }
  }
  __syncthreads();
  int lane = t & 63, w = t >> 6;
  int col = lane & 15, quad = lane >> 4;
  bf16x8_t ah[2][2], al[2][2];
#pragma unroll
  for (int rt = 0; rt < 2; ++rt)
#pragma unroll
    for (int kk = 0; kk < 2; ++kk) {
      int tok = w * 32 + rt * 16 + col;
      int ad = tok * 128 + ((kk * 64 + quad * 16) ^ ((tok & 7) << 4));
      ah[rt][kk] = *(const bf16x8_t*)(smem + ad);
      al[rt][kk] = *(const bf16x8_t*)(smem + 16384 + ad);
    }
  __syncthreads();  // x consumed; smem -> B double-buffer + cn
  float best[2][4], secd[2][4];
  int bi[2][4], si[2][4];
#pragma unroll
  for (int rt = 0; rt < 2; ++rt)
#pragma unroll
    for (int r = 0; r < 4; ++r) {
      best[rt][r] = -3.402823466e+38f; secd[rt][r] = -3.402823466e+38f;
      bi[rt][r] = 0; si[rt][r] = 0;
    }
  int srcoff = (lane * 16) ^ (((lane >> 3) & 7) << 4);  // inverse swizzle
  const unsigned char* ghh = cbh + (size_t)kh * 131072;
  const unsigned char* glh = cbl + (size_t)kh * 131072;
  // stage cn half (4KB, linear) + B tile 0 (wave w -> its 2KB slice)
  glds16((const unsigned char*)ch + kh * 4096 + w * 1024 + lane * 16,
         smem + 32768 + w * 1024);
  glds16(ghh + w * 2048 + srcoff, smem + w * 2048);
  glds16(ghh + w * 2048 + 1024 + srcoff, smem + w * 2048 + 1024);
  glds16(glh + w * 2048 + srcoff, smem + 8192 + w * 2048);
  glds16(glh + w * 2048 + 1024 + srcoff, smem + 8192 + w * 2048 + 1024);
  __syncthreads();
  int swz = (col & 7) << 4;
  int cbo0 = col * 128 + ((quad * 16) ^ swz);
  int cbo1 = col * 128 + ((64 + quad * 16) ^ swz);
  int kcol = kh * 1024 + col;
  const int NT = 16;
  for (int kt = 0; kt < NT; ++kt) {
    unsigned char* bufc = smem + (kt & 1) * 16384;
    unsigned char* bufn = smem + ((kt + 1) & 1) * 16384;
    if (kt + 1 < NT) {
      size_t gof = (size_t)(kt + 1) * 8192 + w * 2048 + srcoff;
      glds16(ghh + gof, bufn + w * 2048);
      glds16(ghh + gof + 1024, bufn + w * 2048 + 1024);
      glds16(glh + gof, bufn + 8192 + w * 2048);
      glds16(glh + gof + 1024, bufn + 8192 + w * 2048 + 1024);
    }
    // per-tile cn prefetch from LDS (4 reads, immediate offsets)
    float cns[4];
    const unsigned char* cnb = smem + 32768 + kt * 256 + col * 4;
#pragma unroll
    for (int j = 0; j < 4; ++j) cns[j] = *(const float*)(cnb + 64 * j);
    int kbt = kcol + kt * 64;
    // 2-deep B-frag pipeline (named after unroll -> registers, rule #20)
    bf16x8_t pbh0[2], pbh1[2], pbl0[2], pbl1[2];
    pbh0[0] = *(const bf16x8_t*)(bufc + cbo0);
    pbh1[0] = *(const bf16x8_t*)(bufc + cbo1);
    pbl0[0] = *(const bf16x8_t*)(bufc + 8192 + cbo0);
    pbl1[0] = *(const bf16x8_t*)(bufc + 8192 + cbo1);
#pragma unroll
    for (int sub = 0; sub < 4; ++sub) {
      int cur = sub & 1, nxt = cur ^ 1;
      if (sub < 3) {  // issue next sub's reads BEFORE this sub's compute
        pbh0[nxt] = *(const bf16x8_t*)(bufc + cbo0 + 2048 * (sub + 1));
        pbh1[nxt] = *(const bf16x8_t*)(bufc + cbo1 + 2048 * (sub + 1));
        pbl0[nxt] = *(const bf16x8_t*)(bufc + 8192 + cbo0 + 2048 * (sub + 1));
        pbl1[nxt] = *(const bf16x8_t*)(bufc + 8192 + cbo1 + 2048 * (sub + 1));
      }
      float cn = cns[sub];
      int kbase = kbt + sub * 16;
#pragma unroll
      for (int rt = 0; rt < 2; ++rt) {
        // two independent 3-chains (halved MFMA dep latency), summed after
        fx4_t a0 = {cn, cn, cn, cn};
        a0 = MFMA16(al[rt][0], pbh0[cur], a0, 0, 0, 0);
        a0 = MFMA16(ah[rt][0], pbl0[cur], a0, 0, 0, 0);
        a0 = MFMA16(ah[rt][0], pbh0[cur], a0, 0, 0, 0);
        fx4_t a1 = {0.f, 0.f, 0.f, 0.f};
        a1 = MFMA16(al[rt][1], pbh1[cur], a1, 0, 0, 0);
        a1 = MFMA16(ah[rt][1], pbl1[cur], a1, 0, 0, 0);
        a1 = MFMA16(ah[rt][1], pbh1[cur], a1, 0, 0, 0);
#pragma unroll
        for (int r = 0; r < 4; ++r) {
          float v = a0[r] + a1[r];
          if (v > best[rt][r]) {
            secd[rt][r] = best[rt][r]; si[rt][r] = bi[rt][r];
            best[rt][r] = v; bi[rt][r] = kbase;
          } else if (v > secd[rt][r]) {
            secd[rt][r] = v; si[rt][r] = kbase;
          }
        }
      }
    }
    __syncthreads();
  }
  // cross-lane merge over 16 cols per token row (lex: max S, min k)
#pragma unroll
  for (int step = 1; step <= 8; step <<= 1) {
#pragma unroll
    for (int rt = 0; rt < 2; ++rt)
#pragma unroll
      for (int r = 0; r < 4; ++r) {
        float ob = __shfl_xor(best[rt][r], step, 64);
        int oi = __shfl_xor(bi[rt][r], step, 64);
        float os = __shfl_xor(secd[rt][r], step, 64);
        int oj = __shfl_xor(si[rt][r], step, 64);
        bool oW = (ob > best[rt][r]) || (ob == best[rt][r] && oi < bi[rt][r]);
        float nb = oW ? ob : best[rt][r];
        int ni = oW ? oi : bi[rt][r];
        float lb = oW ? best[rt][r] : ob;
        int li = oW ? bi[rt][r] : oi;
        float ws = oW ? os : secd[rt][r];
        int wi = oW ? oj : si[rt][r];
        bool sW = (ws > lb) || (ws == lb && wi < li);
        best[rt][r] = nb; bi[rt][r] = ni;
        secd[rt][r] = sW ? ws : lb; si[rt][r] = sW ? wi : li;
      }
  }
  if (col == 0) {
#pragma unroll
    for (int rt = 0; rt < 2; ++rt)
#pragma unroll
      for (int r = 0; r < 4; ++r) {
        int token = n0 + w * 32 + rt * 16 + quad * 4 + r;
        cidx[(size_t)(2 * kh + 0) * NN + token] = bi[rt][r];
        cidx[(size_t)(2 * kh + 1) * NN + token] = si[rt][r];
      }
  }
}

// == kernel 4: fused fp64 select (4 cands) + gather q + losses + conv_out ==
__global__ __launch_bounds__(256, 3) void vq_finish(
    const float* __restrict__ cb, const float* __restrict__ w_out,
    const float* __restrict__ b_out, const int* __restrict__ cidx,
    float* __restrict__ dout, float* __restrict__ loss_acc) {
  __shared__ float qs[CC][BM];
  __shared__ float xs[CC][BM];
  __shared__ float wt[CC][CC];
  __shared__ int ids[BM];
  int t = threadIdx.x;
  int n0 = blockIdx.x * BM;
  int b = n0 >> 14, s0 = n0 & (SS - 1);
  float* zreg = dout + (size_t)NN * CC;
  {  // stage wt transposed
    int o = t >> 2, c0 = (t & 3) * 16;
    const float4* wr = (const float4*)(w_out + o * CC + c0);
#pragma unroll
    for (int i = 0; i < 4; ++i) {
      float4 v = wr[i];
      int ci = c0 + 4 * i;
      wt[ci + 0][o] = v.x; wt[ci + 1][o] = v.y;
      wt[ci + 2][o] = v.z; wt[ci + 3][o] = v.w;
    }
  }
#pragma unroll
  for (int i = 0; i < 4; ++i) {  // stage xs (= xf) from z region
    int e4 = t + 256 * i;
    int ci = e4 >> 4, tok4 = (e4 & 15) * 4;
    *(float4*)&xs[ci][tok4] = *(const float4*)(zreg + (size_t)b * CC * SS +
                                               (size_t)ci * SS + s0 + tok4);
  }
  __syncthreads();
  {  // fused exact fp64 selection: 4 threads per token, lex-min (d, k)
    int tok = t >> 2, cand = t & 3;
    int kj = cidx[(size_t)cand * NN + n0 + tok];
    const float* cp = cb + (size_t)kj * CC;
    double dj = 0.0;
#pragma unroll 8
    for (int c = 0; c < CC; ++c) {
      double df = (double)xs[c][tok] - (double)cp[c];
      dj = fma(df, df, dj);
    }
#pragma unroll
    for (int step = 1; step <= 2; step <<= 1) {
      double od = __shfl_xor(dj, step, 64);
      int ok = __shfl_xor(kj, step, 64);
      if (od < dj || (od == dj && ok < kj)) { dj = od; kj = ok; }
    }
    if (cand == 0) ids[tok] = kj;
  }
  __syncthreads();
  {  // stage qs[ch][tok] = codebook[ids[tok]]
    int tok = t >> 2, c0 = (t & 3) * 16;
    const float4* qr = (const float4*)(cb + (size_t)ids[tok] * CC + c0);
#pragma unroll
    for (int i = 0; i < 4; ++i) {
      float4 v = qr[i];
      int ch = c0 + 4 * i;
      qs[ch + 0][tok] = v.x; qs[ch + 1][tok] = v.y;
      qs[ch + 2][tok] = v.z; qs[ch + 3][tok] = v.w;
    }
  }
  __syncthreads();
  float lsum = 0.f;
#pragma unroll
  for (int i = 0; i < 4; ++i) {  // losses + z := q
    int e4 = t + 256 * i;
    int ci = e4 >> 4, tok4 = (e4 & 15) * 4;
    float4 qv = *(const float4*)&qs[ci][tok4];
    float4 xv = *(const float4*)&xs[ci][tok4];
    float dx = qv.x - xv.x, dy = qv.y - xv.y;
    float dz = qv.z - xv.z, dw = qv.w - xv.w;
    lsum = fmaf(dx, dx, lsum); lsum = fmaf(dy, dy, lsum);
    lsum = fmaf(dz, dz, lsum); lsum = fmaf(dw, dw, lsum);
    *(float4*)(zreg + (size_t)b * CC * SS + (size_t)ci * SS + s0 + tok4) = qv;
  }
  int tx = t & 15, ty = t >> 4;
  float acc[4][4];
#pragma unroll
  for (int j = 0; j < 4; ++j) {
    float bj = b_out[tx * 4 + j];
#pragma unroll
    for (int m = 0; m < 4; ++m) acc[m][j] = bj;
  }
#pragma unroll 8
  for (int ci = 0; ci < CC; ++ci) {
    float4 xq = *(const float4*)&qs[ci][ty * 4];
    float4 wq = *(const float4*)&wt[ci][tx * 4];
    float xm[4] = {xq.x, xq.y, xq.z, xq.w};
    float wm[4] = {wq.x, wq.y, wq.z, wq.w};
#pragma unroll
    for (int m = 0; m < 4; ++m)
#pragma unroll
      for (int j = 0; j < 4; ++j) acc[m][j] = fmaf(xm[m], wm[j], acc[m][j]);
  }
#pragma unroll
  for (int j = 0; j < 4; ++j) {
    float4 ov = make_float4(acc[0][j], acc[1][j], acc[2][j], acc[3][j]);
    *(float4*)(dout + (size_t)b * CC * SS + (size_t)(tx * 4 + j) * SS + s0 +
               ty * 4) = ov;
  }
#pragma unroll
  for (int off = 32; off > 0; off >>= 1) lsum += __shfl_down(lsum, off, 64);
  __shared__ float wsum[4];
  if ((t & 63) == 0) wsum[t >> 6] = lsum;
  __syncthreads();
  if (t == 0) atomicAdd(loss_acc, wsum[0] + wsum[1] + wsum[2] + wsum[3]);
}

// ============ kernel 5: finalize scalar losses ============
__global__ void vq_finalize(const float* __restrict__ loss_acc,
                            float* __restrict__ dout) {
  float l = loss_acc[0] * (1.0f / (float)((size_t)NN * CC));
  dout[(size_t)2 * NN * CC + 0] = l;  // codebook_loss
  dout[(size_t)2 * NN * CC + 1] = l;  // commitment_loss
}

extern "C" void kernel_launch(void* const* d_in, const int* in_sizes, int n_in,
                              void* d_out, int out_size, void* d_ws,
                              size_t ws_size, hipStream_t stream) {
  const float* x = (const float*)d_in[0];
  const float* cb = (const float*)d_in[1];
  const float* w_in = (const float*)d_in[2];
  const float* b_in = (const float*)d_in[3];
  const float* w_out = (const float*)d_in[4];
  const float* b_out = (const float*)d_in[5];
  float* out = (float*)d_out;
  float* zreg = out + (size_t)NN * CC;  // z region doubles as xf scratch

  // ws: [0,4) loss; [1024,9216) ch; [16K,272K) cbh; [272K,528K) cbl;
  //     [528K,1552K) cidx (4 planes x NN). ~1.6 MB total.
  float* loss_acc = (float*)d_ws;
  float* ch = (float*)((char*)d_ws + 1024);
  unsigned short* cbh = (unsigned short*)((char*)d_ws + 16384);
  unsigned short* cbl = (unsigned short*)((char*)d_ws + 16384 + 262144);
  int* cidx = (int*)((char*)d_ws + 16384 + 2 * 262144);

  hipMemsetAsync(d_ws, 0, 4, stream);

  vq_conv_in<<<NN / BM, 256, 0, stream>>>(x, w_in, b_in, zreg);
  vq_split<<<KK / 256, 256, 0, stream>>>(cb, cbh, cbl, ch);
  vq_mfma_argmin<<<(NN / BMA) * 2, 256, 0, stream>>>(
      zreg, (const unsigned char*)cbh, (const unsigned char*)cbl, ch, cidx);
  vq_finish<<<NN / BM, 256, 0, stream>>>(cb, w_out, b_out, cidx, out,
                                         loss_acc);
  vq_finalize<<<1, 1, 0, stream>>>(loss_acc, out);
}

// Round 11
// 137.870 us; speedup vs baseline: 1.0685x; 1.0587x over previous
//
#include <hip/hip_runtime.h>

#define CC 64      // channels
#define SS 16384   // D*W*H
#define NN 65536   // B*S tokens
#define KK 2048    // codebook size
#define BM 64      // tokens per block tile (conv/finish)
#define BMA 128    // tokens per argmin block

typedef __attribute__((ext_vector_type(8))) short bf16x8_t;
typedef __attribute__((ext_vector_type(4))) float fx4_t;
#define MFMA16 __builtin_amdgcn_mfma_f32_16x16x32_bf16

__device__ __forceinline__ unsigned short f2bf(float f) {
  unsigned u = __builtin_bit_cast(unsigned, f);
  return (unsigned short)((u + 0x7fff + ((u >> 16) & 1)) >> 16);  // RNE
}
__device__ __forceinline__ float bf2f(unsigned short h) {
  unsigned u = (unsigned)h << 16;
  return __builtin_bit_cast(float, u);
}
__device__ __forceinline__ void glds16(const void* g, void* l) {
  __builtin_amdgcn_global_load_lds(
      (const __attribute__((address_space(1))) unsigned*)g,
      (__attribute__((address_space(3))) unsigned*)l, 16, 0, 0);
}

// ======= kernel 1: pre = W_in@x + b_in (fp64) + emit bf16-split xh/xl ====
// xf fp32 correctly-rounded (channel-major, for fp64 rerank + finish);
// xh/xl bf16 token-major [tok][64] (argmin A-frags read straight from L2).
__global__ __launch_bounds__(256, 4) void vq_conv_in(
    const float* __restrict__ x, const float* __restrict__ w_in,
    const float* __restrict__ b_in, float* __restrict__ xf,
    unsigned short* __restrict__ xh, unsigned short* __restrict__ xl) {
  __shared__ float xs[CC][BM];
  __shared__ float wt[CC][CC];
  int t = threadIdx.x;
  int n0 = blockIdx.x * BM;
  int b = n0 >> 14, s0 = n0 & (SS - 1);
  {
    int o = t >> 2, c0 = (t & 3) * 16;
    const float4* wr = (const float4*)(w_in + o * CC + c0);
#pragma unroll
    for (int i = 0; i < 4; ++i) {
      float4 v = wr[i];
      int ci = c0 + 4 * i;
      wt[ci + 0][o] = v.x; wt[ci + 1][o] = v.y;
      wt[ci + 2][o] = v.z; wt[ci + 3][o] = v.w;
    }
  }
#pragma unroll
  for (int i = 0; i < 4; ++i) {
    int e4 = t + 256 * i;
    int ci = e4 >> 4, tok4 = (e4 & 15) * 4;
    *(float4*)&xs[ci][tok4] =
        *(const float4*)(x + (size_t)b * CC * SS + (size_t)ci * SS + s0 + tok4);
  }
  __syncthreads();
  int tx = t & 15, ty = t >> 4;
  double acc[4][4];
#pragma unroll
  for (int j = 0; j < 4; ++j) {
    double bj = (double)b_in[tx * 4 + j];
#pragma unroll
    for (int m = 0; m < 4; ++m) acc[m][j] = bj;
  }
#pragma unroll 8
  for (int ci = 0; ci < CC; ++ci) {
    float4 xq = *(const float4*)&xs[ci][ty * 4];
    float4 wq = *(const float4*)&wt[ci][tx * 4];
    double xm[4] = {xq.x, xq.y, xq.z, xq.w};
    double wm[4] = {wq.x, wq.y, wq.z, wq.w};
#pragma unroll
    for (int m = 0; m < 4; ++m)
#pragma unroll
      for (int j = 0; j < 4; ++j) acc[m][j] = fma(xm[m], wm[j], acc[m][j]);
  }
#pragma unroll
  for (int j = 0; j < 4; ++j) {
    float4 ov = make_float4((float)acc[0][j], (float)acc[1][j],
                            (float)acc[2][j], (float)acc[3][j]);
    *(float4*)(xf + (size_t)b * CC * SS + (size_t)(tx * 4 + j) * SS + s0 +
               ty * 4) = ov;
  }
  // emit bf16 hi/lo, token-major: xh[tok*64 + tx*4 + j]
#pragma unroll
  for (int m = 0; m < 4; ++m) {
    size_t tok = (size_t)n0 + ty * 4 + m;
    unsigned short h[4], l[4];
#pragma unroll
    for (int j = 0; j < 4; ++j) {
      float v = (float)acc[m][j];
      h[j] = f2bf(v);
      l[j] = f2bf(v - bf2f(h[j]));
    }
    uint2 wh = make_uint2((unsigned)h[0] | ((unsigned)h[1] << 16),
                          (unsigned)h[2] | ((unsigned)h[3] << 16));
    uint2 wl = make_uint2((unsigned)l[0] | ((unsigned)l[1] << 16),
                          (unsigned)l[2] | ((unsigned)l[3] << 16));
    *(uint2*)(xh + tok * CC + tx * 4) = wh;
    *(uint2*)(xl + tok * CC + tx * 4) = wl;
  }
}

// ===== kernel 2: split codebook to bf16 hi/lo + ch = -0.5*||c||^2 =======
__global__ __launch_bounds__(256) void vq_split(
    const float* __restrict__ cb, unsigned short* __restrict__ cbh,
    unsigned short* __restrict__ cbl, float* __restrict__ ch) {
  int k = blockIdx.x * 256 + threadIdx.x;
  const float4* r = (const float4*)(cb + (size_t)k * CC);
  unsigned* oh = (unsigned*)(cbh + (size_t)k * CC);
  unsigned* ol = (unsigned*)(cbl + (size_t)k * CC);
  float s = 0.f;
#pragma unroll
  for (int i = 0; i < 16; ++i) {
    float4 v = r[i];
    float vv[4] = {v.x, v.y, v.z, v.w};
    unsigned short h[4], l[4];
#pragma unroll
    for (int u = 0; u < 4; ++u) {
      s = fmaf(vv[u], vv[u], s);
      h[u] = f2bf(vv[u]);
      l[u] = f2bf(vv[u] - bf2f(h[u]));
    }
    oh[2 * i + 0] = (unsigned)h[0] | ((unsigned)h[1] << 16);
    oh[2 * i + 1] = (unsigned)h[2] | ((unsigned)h[3] << 16);
    ol[2 * i + 0] = (unsigned)l[0] | ((unsigned)l[1] << 16);
    ol[2 * i + 1] = (unsigned)l[2] | ((unsigned)l[3] << 16);
  }
  ch[k] = -0.5f * s;
}

// ====== kernel 3: MFMA scan, 18KB LDS for 8 blocks/CU occupancy ==========
// blockIdx bits[1:0] = K-quarter (512 codes, 16 tiles of 32); rest = token
// group of 128. A-frags direct from global xh/xl (token-major, L2-hot).
// B tiles (32 codes: 4KB hi + 4KB lo) double-buffered via glds w/ inverse-
// swizzled source; cn staged once. LDS = 2*8KB + 2KB = 18KB and VGPR<=64
// (R9 measured 60) -> 8 blocks/CU (m69: <=64 VGPR = 32 waves/CU). No
// source pipelining (R10: compiler spills it to scratch). Top-2 per
// quarter -> 8 cands, fp64 rerank fused in finish.
__global__ __launch_bounds__(256, 4) void vq_mfma_argmin(
    const unsigned short* __restrict__ xh, const unsigned short* __restrict__ xl,
    const unsigned char* __restrict__ cbh, const unsigned char* __restrict__ cbl,
    const float* __restrict__ ch, int* __restrict__ cidx) {
  __shared__ __align__(16) unsigned char smem[18432];  // 2x8KB dbuf + 2KB cn
  int t = threadIdx.x;
  int q = blockIdx.x & 3;
  int n0 = (blockIdx.x >> 2) * BMA;
  int lane = t & 63, w = t >> 6;
  int col = lane & 15, quad = lane >> 4;
  // ---- A-frags direct from global (tok*128B; kk*64 + quad*16 within) ----
  bf16x8_t ah[2][2], al[2][2];
#pragma unroll
  for (int rt = 0; rt < 2; ++rt)
#pragma unroll
    for (int kk = 0; kk < 2; ++kk) {
      size_t byo = ((size_t)n0 + w * 32 + rt * 16 + col) * 128 + kk * 64 +
                   quad * 16;
      ah[rt][kk] = *(const bf16x8_t*)((const unsigned char*)xh + byo);
      al[rt][kk] = *(const bf16x8_t*)((const unsigned char*)xl + byo);
    }
  // ---- stage cn (2KB) + B tile 0 (4KB hi + 4KB lo; wave w -> 1KB each) --
  const unsigned char* ghh = cbh + (size_t)q * 65536;
  const unsigned char* glh = cbl + (size_t)q * 65536;
  int srcoff = (lane * 16) ^ (((lane >> 3) & 7) << 4);  // inverse swizzle
  if (w < 2)
    glds16((const unsigned char*)ch + q * 2048 + w * 1024 + lane * 16,
           smem + 16384 + w * 1024);
  glds16(ghh + w * 1024 + srcoff, smem + w * 1024);
  glds16(glh + w * 1024 + srcoff, smem + 4096 + w * 1024);
  __syncthreads();
  float best[2][4], secd[2][4];
  int bi[2][4], si[2][4];
#pragma unroll
  for (int rt = 0; rt < 2; ++rt)
#pragma unroll
    for (int r = 0; r < 4; ++r) {
      best[rt][r] = -3.402823466e+38f; secd[rt][r] = -3.402823466e+38f;
      bi[rt][r] = 0; si[rt][r] = 0;
    }
  int swz = (col & 7) << 4;
  int cbo0 = col * 128 + ((quad * 16) ^ swz);
  int cbo1 = col * 128 + ((64 + quad * 16) ^ swz);
  int kcol = q * 512 + col;
  const int NT = 16;  // 16 tiles x 32 codes
  for (int kt = 0; kt < NT; ++kt) {
    unsigned char* bufc = smem + (kt & 1) * 8192;
    unsigned char* bufn = smem + ((kt + 1) & 1) * 8192;
    if (kt + 1 < NT) {
      size_t gof = (size_t)(kt + 1) * 4096 + w * 1024 + srcoff;
      glds16(ghh + gof, bufn + w * 1024);
      glds16(glh + gof, bufn + 4096 + w * 1024);
    }
    const unsigned char* cnb = smem + 16384 + kt * 128 + col * 4;
    int kbt = kcol + kt * 32;
#pragma unroll
    for (int sub = 0; sub < 2; ++sub) {
      bf16x8_t bh0 = *(const bf16x8_t*)(bufc + cbo0 + 2048 * sub);
      bf16x8_t bh1 = *(const bf16x8_t*)(bufc + cbo1 + 2048 * sub);
      bf16x8_t bl0 = *(const bf16x8_t*)(bufc + 4096 + cbo0 + 2048 * sub);
      bf16x8_t bl1 = *(const bf16x8_t*)(bufc + 4096 + cbo1 + 2048 * sub);
      float cn = *(const float*)(cnb + 64 * sub);
      int kbase = kbt + sub * 16;
#pragma unroll
      for (int rt = 0; rt < 2; ++rt) {
        fx4_t acc = {cn, cn, cn, cn};
        acc = MFMA16(al[rt][0], bh0, acc, 0, 0, 0);  // lh
        acc = MFMA16(al[rt][1], bh1, acc, 0, 0, 0);
        acc = MFMA16(ah[rt][0], bl0, acc, 0, 0, 0);  // hl
        acc = MFMA16(ah[rt][1], bl1, acc, 0, 0, 0);
        acc = MFMA16(ah[rt][0], bh0, acc, 0, 0, 0);  // hh
        acc = MFMA16(ah[rt][1], bh1, acc, 0, 0, 0);
#pragma unroll
        for (int r = 0; r < 4; ++r) {
          float v = acc[r];
          if (v > best[rt][r]) {
            secd[rt][r] = best[rt][r]; si[rt][r] = bi[rt][r];
            best[rt][r] = v; bi[rt][r] = kbase;
          } else if (v > secd[rt][r]) {
            secd[rt][r] = v; si[rt][r] = kbase;
          }
        }
      }
    }
    __syncthreads();
  }
  // cross-lane merge over 16 cols per token row (lex: max S, min k)
#pragma unroll
  for (int step = 1; step <= 8; step <<= 1) {
#pragma unroll
    for (int rt = 0; rt < 2; ++rt)
#pragma unroll
      for (int r = 0; r < 4; ++r) {
        float ob = __shfl_xor(best[rt][r], step, 64);
        int oi = __shfl_xor(bi[rt][r], step, 64);
        float os = __shfl_xor(secd[rt][r], step, 64);
        int oj = __shfl_xor(si[rt][r], step, 64);
        bool oW = (ob > best[rt][r]) || (ob == best[rt][r] && oi < bi[rt][r]);
        float nb = oW ? ob : best[rt][r];
        int ni = oW ? oi : bi[rt][r];
        float lb = oW ? best[rt][r] : ob;
        int li = oW ? bi[rt][r] : oi;
        float ws = oW ? os : secd[rt][r];
        int wi = oW ? oj : si[rt][r];
        bool sW = (ws > lb) || (ws == lb && wi < li);
        best[rt][r] = nb; bi[rt][r] = ni;
        secd[rt][r] = sW ? ws : lb; si[rt][r] = sW ? wi : li;
      }
  }
  if (col == 0) {
#pragma unroll
    for (int rt = 0; rt < 2; ++rt)
#pragma unroll
      for (int r = 0; r < 4; ++r) {
        int token = n0 + w * 32 + rt * 16 + quad * 4 + r;
        cidx[(size_t)(2 * q + 0) * NN + token] = bi[rt][r];
        cidx[(size_t)(2 * q + 1) * NN + token] = si[rt][r];
      }
  }
}

// == kernel 4: fused fp64 select (8 cands) + gather q + losses + conv_out ==
__global__ __launch_bounds__(256, 3) void vq_finish(
    const float* __restrict__ cb, const float* __restrict__ w_out,
    const float* __restrict__ b_out, const int* __restrict__ cidx,
    float* __restrict__ dout, float* __restrict__ loss_acc) {
  __shared__ float qs[CC][BM];
  __shared__ float xs[CC][BM];
  __shared__ float wt[CC][CC];
  __shared__ int ids[BM];
  int t = threadIdx.x;
  int n0 = blockIdx.x * BM;
  int b = n0 >> 14, s0 = n0 & (SS - 1);
  float* zreg = dout + (size_t)NN * CC;
  {  // stage wt transposed
    int o = t >> 2, c0 = (t & 3) * 16;
    const float4* wr = (const float4*)(w_out + o * CC + c0);
#pragma unroll
    for (int i = 0; i < 4; ++i) {
      float4 v = wr[i];
      int ci = c0 + 4 * i;
      wt[ci + 0][o] = v.x; wt[ci + 1][o] = v.y;
      wt[ci + 2][o] = v.z; wt[ci + 3][o] = v.w;
    }
  }
#pragma unroll
  for (int i = 0; i < 4; ++i) {  // stage xs (= xf) from z region
    int e4 = t + 256 * i;
    int ci = e4 >> 4, tok4 = (e4 & 15) * 4;
    *(float4*)&xs[ci][tok4] = *(const float4*)(zreg + (size_t)b * CC * SS +
                                               (size_t)ci * SS + s0 + tok4);
  }
  __syncthreads();
  {  // fused exact fp64 selection: 4 threads/token, 2 cands each, lex-min
    int tok = t >> 2, cp = t & 3;
    int k0 = cidx[(size_t)cp * NN + n0 + tok];
    int k1 = cidx[(size_t)(cp + 4) * NN + n0 + tok];
    const float* c0p = cb + (size_t)k0 * CC;
    const float* c1p = cb + (size_t)k1 * CC;
    double d0 = 0.0, d1 = 0.0;
#pragma unroll 8
    for (int c = 0; c < CC; ++c) {
      double xv = (double)xs[c][tok];
      double f0 = xv - (double)c0p[c];
      double f1 = xv - (double)c1p[c];
      d0 = fma(f0, f0, d0);
      d1 = fma(f1, f1, d1);
    }
    double dj = d0; int kj = k0;
    if (d1 < dj || (d1 == dj && k1 < kj)) { dj = d1; kj = k1; }
#pragma unroll
    for (int step = 1; step <= 2; step <<= 1) {
      double od = __shfl_xor(dj, step, 64);
      int ok = __shfl_xor(kj, step, 64);
      if (od < dj || (od == dj && ok < kj)) { dj = od; kj = ok; }
    }
    if (cp == 0) ids[tok] = kj;
  }
  __syncthreads();
  {  // stage qs[ch][tok] = codebook[ids[tok]]
    int tok = t >> 2, c0 = (t & 3) * 16;
    const float4* qr = (const float4*)(cb + (size_t)ids[tok] * CC + c0);
#pragma unroll
    for (int i = 0; i < 4; ++i) {
      float4 v = qr[i];
      int ch = c0 + 4 * i;
      qs[ch + 0][tok] = v.x; qs[ch + 1][tok] = v.y;
      qs[ch + 2][tok] = v.z; qs[ch + 3][tok] = v.w;
    }
  }
  __syncthreads();
  float lsum = 0.f;
#pragma unroll
  for (int i = 0; i < 4; ++i) {  // losses + z := q
    int e4 = t + 256 * i;
    int ci = e4 >> 4, tok4 = (e4 & 15) * 4;
    float4 qv = *(const float4*)&qs[ci][tok4];
    float4 xv = *(const float4*)&xs[ci][tok4];
    float dx = qv.x - xv.x, dy = qv.y - xv.y;
    float dz = qv.z - xv.z, dw = qv.w - xv.w;
    lsum = fmaf(dx, dx, lsum); lsum = fmaf(dy, dy, lsum);
    lsum = fmaf(dz, dz, lsum); lsum = fmaf(dw, dw, lsum);
    *(float4*)(zreg + (size_t)b * CC * SS + (size_t)ci * SS + s0 + tok4) = qv;
  }
  int tx = t & 15, ty = t >> 4;
  float acc[4][4];
#pragma unroll
  for (int j = 0; j < 4; ++j) {
    float bj = b_out[tx * 4 + j];
#pragma unroll
    for (int m = 0; m < 4; ++m) acc[m][j] = bj;
  }
#pragma unroll 8
  for (int ci = 0; ci < CC; ++ci) {
    float4 xq = *(const float4*)&qs[ci][ty * 4];
    float4 wq = *(const float4*)&wt[ci][tx * 4];
    float xm[4] = {xq.x, xq.y, xq.z, xq.w};
    float wm[4] = {wq.x, wq.y, wq.z, wq.w};
#pragma unroll
    for (int m = 0; m < 4; ++m)
#pragma unroll
      for (int j = 0; j < 4; ++j) acc[m][j] = fmaf(xm[m], wm[j], acc[m][j]);
  }
#pragma unroll
  for (int j = 0; j < 4; ++j) {
    float4 ov = make_float4(acc[0][j], acc[1][j], acc[2][j], acc[3][j]);
    *(float4*)(dout + (size_t)b * CC * SS + (size_t)(tx * 4 + j) * SS + s0 +
               ty * 4) = ov;
  }
#pragma unroll
  for (int off = 32; off > 0; off >>= 1) lsum += __shfl_down(lsum, off, 64);
  __shared__ float wsum[4];
  if ((t & 63) == 0) wsum[t >> 6] = lsum;
  __syncthreads();
  if (t == 0) atomicAdd(loss_acc, wsum[0] + wsum[1] + wsum[2] + wsum[3]);
}

// ============ kernel 5: finalize scalar losses ============
__global__ void vq_finalize(const float* __restrict__ loss_acc,
                            float* __restrict__ dout) {
  float l = loss_acc[0] * (1.0f / (float)((size_t)NN * CC));
  dout[(size_t)2 * NN * CC + 0] = l;  // codebook_loss
  dout[(size_t)2 * NN * CC + 1] = l;  // commitment_loss
}

extern "C" void kernel_launch(void* const* d_in, const int* in_sizes, int n_in,
                              void* d_out, int out_size, void* d_ws,
                              size_t ws_size, hipStream_t stream) {
  const float* x = (const float*)d_in[0];
  const float* cb = (const float*)d_in[1];
  const float* w_in = (const float*)d_in[2];
  const float* b_in = (const float*)d_in[3];
  const float* w_out = (const float*)d_in[4];
  const float* b_out = (const float*)d_in[5];
  float* out = (float*)d_out;
  float* zreg = out + (size_t)NN * CC;  // z region doubles as xf scratch
  // out region doubles as xh/xl scratch (16.77MB, overwritten by finish)
  unsigned short* xh = (unsigned short*)out;
  unsigned short* xl = xh + (size_t)NN * CC;

  // ws: [0,4) loss; [1024,9216) ch; [16K,272K) cbh; [272K,528K) cbl;
  //     [528K,2576K) cidx (8 planes x NN). ~2.6 MB total.
  float* loss_acc = (float*)d_ws;
  float* ch = (float*)((char*)d_ws + 1024);
  unsigned short* cbh = (unsigned short*)((char*)d_ws + 16384);
  unsigned short* cbl = (unsigned short*)((char*)d_ws + 16384 + 262144);
  int* cidx = (int*)((char*)d_ws + 16384 + 2 * 262144);

  hipMemsetAsync(d_ws, 0, 4, stream);

  vq_conv_in<<<NN / BM, 256, 0, stream>>>(x, w_in, b_in, zreg, xh, xl);
  vq_split<<<KK / 256, 256, 0, stream>>>(cb, cbh, cbl, ch);
  vq_mfma_argmin<<<(NN / BMA) * 4, 256, 0, stream>>>(
      xh, xl, (const unsigned char*)cbh, (const unsigned char*)cbl, ch, cidx);
  vq_finish<<<NN / BM, 256, 0, stream>>>(cb, w_out, b_out, cidx, out,
                                         loss_acc);
  vq_finalize<<<1, 1, 0, stream>>>(loss_acc, out);
}

// Round 12
// 112.604 us; speedup vs baseline: 1.3082x; 1.2244x over previous
//
#include <hip/hip_runtime.h>

#define CC 64      // channels
#define SS 16384   // D*W*H
#define NN 65536   // B*S tokens
#define KK 2048    // codebook size
#define BM 64      // tokens per block tile (conv/finish)
#define BMA 128    // tokens per argmin block

typedef __attribute__((ext_vector_type(8))) short bf16x8_t;
typedef __attribute__((ext_vector_type(4))) float fx4_t;
#define MFMA16 __builtin_amdgcn_mfma_f32_16x16x32_bf16

__device__ __forceinline__ unsigned short f2bf(float f) {
  unsigned u = __builtin_bit_cast(unsigned, f);
  return (unsigned short)((u + 0x7fff + ((u >> 16) & 1)) >> 16);  // RNE
}
__device__ __forceinline__ float bf2f(unsigned short h) {
  unsigned u = (unsigned)h << 16;
  return __builtin_bit_cast(float, u);
}
__device__ __forceinline__ void glds16(const void* g, void* l) {
  __builtin_amdgcn_global_load_lds(
      (const __attribute__((address_space(1))) unsigned*)g,
      (__attribute__((address_space(3))) unsigned*)l, 16, 0, 0);
}

// ============ kernel 1: pre = W_in @ x + b_in (fp64 accum, 4x4 tile) =====
__global__ __launch_bounds__(256, 4) void vq_conv_in(
    const float* __restrict__ x, const float* __restrict__ w_in,
    const float* __restrict__ b_in, float* __restrict__ xf) {
  __shared__ float xs[CC][BM];
  __shared__ float wt[CC][CC];
  int t = threadIdx.x;
  int n0 = blockIdx.x * BM;
  int b = n0 >> 14, s0 = n0 & (SS - 1);
  {
    int o = t >> 2, c0 = (t & 3) * 16;
    const float4* wr = (const float4*)(w_in + o * CC + c0);
#pragma unroll
    for (int i = 0; i < 4; ++i) {
      float4 v = wr[i];
      int ci = c0 + 4 * i;
      wt[ci + 0][o] = v.x; wt[ci + 1][o] = v.y;
      wt[ci + 2][o] = v.z; wt[ci + 3][o] = v.w;
    }
  }
#pragma unroll
  for (int i = 0; i < 4; ++i) {
    int e4 = t + 256 * i;
    int ci = e4 >> 4, tok4 = (e4 & 15) * 4;
    *(float4*)&xs[ci][tok4] =
        *(const float4*)(x + (size_t)b * CC * SS + (size_t)ci * SS + s0 + tok4);
  }
  __syncthreads();
  int tx = t & 15, ty = t >> 4;
  double acc[4][4];
#pragma unroll
  for (int j = 0; j < 4; ++j) {
    double bj = (double)b_in[tx * 4 + j];
#pragma unroll
    for (int m = 0; m < 4; ++m) acc[m][j] = bj;
  }
#pragma unroll 8
  for (int ci = 0; ci < CC; ++ci) {
    float4 xq = *(const float4*)&xs[ci][ty * 4];
    float4 wq = *(const float4*)&wt[ci][tx * 4];
    double xm[4] = {xq.x, xq.y, xq.z, xq.w};
    double wm[4] = {wq.x, wq.y, wq.z, wq.w};
#pragma unroll
    for (int m = 0; m < 4; ++m)
#pragma unroll
      for (int j = 0; j < 4; ++j) acc[m][j] = fma(xm[m], wm[j], acc[m][j]);
  }
#pragma unroll
  for (int j = 0; j < 4; ++j) {
    float4 ov = make_float4((float)acc[0][j], (float)acc[1][j],
                            (float)acc[2][j], (float)acc[3][j]);
    *(float4*)(xf + (size_t)b * CC * SS + (size_t)(tx * 4 + j) * SS + s0 +
               ty * 4) = ov;
  }
}

// ===== kernel 2: split codebook to bf16 hi/lo + ch = -0.5*||c||^2 =======
__global__ __launch_bounds__(256) void vq_split(
    const float* __restrict__ cb, unsigned short* __restrict__ cbh,
    unsigned short* __restrict__ cbl, float* __restrict__ ch) {
  int k = blockIdx.x * 256 + threadIdx.x;
  const float4* r = (const float4*)(cb + (size_t)k * CC);
  unsigned* oh = (unsigned*)(cbh + (size_t)k * CC);
  unsigned* ol = (unsigned*)(cbl + (size_t)k * CC);
  float s = 0.f;
#pragma unroll
  for (int i = 0; i < 16; ++i) {
    float4 v = r[i];
    float vv[4] = {v.x, v.y, v.z, v.w};
    unsigned short h[4], l[4];
#pragma unroll
    for (int u = 0; u < 4; ++u) {
      s = fmaf(vv[u], vv[u], s);
      h[u] = f2bf(vv[u]);
      l[u] = f2bf(vv[u] - bf2f(h[u]));
    }
    oh[2 * i + 0] = (unsigned)h[0] | ((unsigned)h[1] << 16);
    oh[2 * i + 1] = (unsigned)h[2] | ((unsigned)h[3] << 16);
    ol[2 * i + 0] = (unsigned)l[0] | ((unsigned)l[1] << 16);
    ol[2 * i + 1] = (unsigned)l[2] | ((unsigned)l[3] << 16);
  }
  ch[k] = -0.5f * s;
}

// ====== kernel 3: MFMA scan (R8 structure), best-only in-loop select =====
// blockIdx bit0 = K-half; 16 tiles of 64 codes, B dbuf via glds (inverse-
// swizzled source), cn staged in LDS. In-loop select = best-only per column
// (3 VALU/value: cmp + 2 cndmask); top-2 recovered at the 16-column merge.
// Safety: true argmin lost only if beaten within ITS OWN column by < bf16-
// split noise (~1e-5) -> prob ~ (old flip risk)/16; fp64 rerank fixes rest.
__global__ __launch_bounds__(256, 4) void vq_mfma_argmin(
    const float* __restrict__ xf, const unsigned char* __restrict__ cbh,
    const unsigned char* __restrict__ cbl, const float* __restrict__ ch,
    int* __restrict__ cidx) {
  __shared__ __align__(16) unsigned char smem[36864];  // 32K x/Bdbuf + 4K cn
  int t = threadIdx.x;
  int kh = blockIdx.x & 1;
  int n0 = (blockIdx.x >> 1) * BMA;
  int b = n0 >> 14, s0 = n0 & (SS - 1);
  int lane = t & 63, w = t >> 6;
  // stage this half's cn (4KB) into LDS [32768..36864) — overlaps phase A
  glds16((const unsigned char*)ch + kh * 4096 + w * 1024 + lane * 16,
         smem + 32768 + w * 1024);
  // ---- phase A: stage x as bf16 hi/lo token-major, swizzled ----
  {
    int tok = t & 127;
    int half = t >> 7;
    const float* xb = xf + (size_t)b * CC * SS + s0 + tok;
#pragma unroll
    for (int i = 0; i < 4; ++i) {
      int c0 = half * 32 + i * 8;
      bf16x8_t h8, l8;
#pragma unroll
      for (int j = 0; j < 8; ++j) {
        float v = xb[(size_t)(c0 + j) * SS];
        unsigned short hs = f2bf(v);
        h8[j] = (short)hs;
        l8[j] = (short)f2bf(v - bf2f(hs));
      }
      int ad = tok * 128 + ((half * 64 + i * 16) ^ ((tok & 7) << 4));
      *(bf16x8_t*)(smem + ad) = h8;
      *(bf16x8_t*)(smem + 16384 + ad) = l8;
    }
  }
  __syncthreads();
  int col = lane & 15, quad = lane >> 4;
  bf16x8_t ah[2][2], al[2][2];
#pragma unroll
  for (int rt = 0; rt < 2; ++rt)
#pragma unroll
    for (int kk = 0; kk < 2; ++kk) {
      int tok = w * 32 + rt * 16 + col;
      int ad = tok * 128 + ((kk * 64 + quad * 16) ^ ((tok & 7) << 4));
      ah[rt][kk] = *(const bf16x8_t*)(smem + ad);
      al[rt][kk] = *(const bf16x8_t*)(smem + 16384 + ad);
    }
  __syncthreads();  // x consumed; smem[0..32K) -> B double-buffer
  float best[2][4];
  int bi[2][4];
#pragma unroll
  for (int rt = 0; rt < 2; ++rt)
#pragma unroll
    for (int r = 0; r < 4; ++r) {
      best[rt][r] = -3.402823466e+38f;
      bi[rt][r] = 0;
    }
  int srcoff = (lane * 16) ^ (((lane >> 3) & 7) << 4);  // inverse swizzle
  const unsigned char* ghh = cbh + (size_t)kh * 131072;
  const unsigned char* glh = cbl + (size_t)kh * 131072;
  // prologue: B tile 0 (64 codes: hi 8KB + lo 8KB; wave w -> 2KB each)
  glds16(ghh + w * 2048 + srcoff, smem + w * 2048);
  glds16(ghh + w * 2048 + 1024 + srcoff, smem + w * 2048 + 1024);
  glds16(glh + w * 2048 + srcoff, smem + 8192 + w * 2048);
  glds16(glh + w * 2048 + 1024 + srcoff, smem + 8192 + w * 2048 + 1024);
  __syncthreads();
  int swz = (col & 7) << 4;
  int cbo0 = col * 128 + ((quad * 16) ^ swz);
  int cbo1 = col * 128 + ((64 + quad * 16) ^ swz);
  int kcol = kh * 1024 + col;
  const int NT = 16;
  for (int kt = 0; kt < NT; ++kt) {
    unsigned char* bufc = smem + (kt & 1) * 16384;
    unsigned char* bufn = smem + ((kt + 1) & 1) * 16384;
    if (kt + 1 < NT) {
      size_t gof = (size_t)(kt + 1) * 8192 + w * 2048 + srcoff;
      glds16(ghh + gof, bufn + w * 2048);
      glds16(ghh + gof + 1024, bufn + w * 2048 + 1024);
      glds16(glh + gof, bufn + 8192 + w * 2048);
      glds16(glh + gof + 1024, bufn + 8192 + w * 2048 + 1024);
    }
    const unsigned char* cnb = smem + 32768 + kt * 256 + col * 4;
    int kbt = kcol + kt * 64;
#pragma unroll
    for (int sub = 0; sub < 4; ++sub) {
      bf16x8_t bh0 = *(const bf16x8_t*)(bufc + cbo0 + 2048 * sub);
      bf16x8_t bh1 = *(const bf16x8_t*)(bufc + cbo1 + 2048 * sub);
      bf16x8_t bl0 = *(const bf16x8_t*)(bufc + 8192 + cbo0 + 2048 * sub);
      bf16x8_t bl1 = *(const bf16x8_t*)(bufc + 8192 + cbo1 + 2048 * sub);
      float cn = *(const float*)(cnb + 64 * sub);
      int kbase = kbt + sub * 16;
#pragma unroll
      for (int rt = 0; rt < 2; ++rt) {
        fx4_t acc = {cn, cn, cn, cn};
        acc = MFMA16(al[rt][0], bh0, acc, 0, 0, 0);  // lh
        acc = MFMA16(al[rt][1], bh1, acc, 0, 0, 0);
        acc = MFMA16(ah[rt][0], bl0, acc, 0, 0, 0);  // hl
        acc = MFMA16(ah[rt][1], bl1, acc, 0, 0, 0);
        acc = MFMA16(ah[rt][0], bh0, acc, 0, 0, 0);  // hh
        acc = MFMA16(ah[rt][1], bh1, acc, 0, 0, 0);
        // best-only select: 3 VALU per value (ascending k + strict > ==
        // first-occurrence within the column)
#pragma unroll
        for (int r = 0; r < 4; ++r) {
          float v = acc[r];
          bool g = v > best[rt][r];
          best[rt][r] = g ? v : best[rt][r];
          bi[rt][r] = g ? kbase : bi[rt][r];
        }
      }
    }
    __syncthreads();
  }
  // 16-column merge with top-2 recovery (lex: max S, min k)
  float secd[2][4];
  int si[2][4];
#pragma unroll
  for (int rt = 0; rt < 2; ++rt)
#pragma unroll
    for (int r = 0; r < 4; ++r) {
      secd[rt][r] = -3.402823466e+38f;
      si[rt][r] = 0x7fffffff;
    }
#pragma unroll
  for (int step = 1; step <= 8; step <<= 1) {
#pragma unroll
    for (int rt = 0; rt < 2; ++rt)
#pragma unroll
      for (int r = 0; r < 4; ++r) {
        float ob = __shfl_xor(best[rt][r], step, 64);
        int oi = __shfl_xor(bi[rt][r], step, 64);
        float os = __shfl_xor(secd[rt][r], step, 64);
        int oj = __shfl_xor(si[rt][r], step, 64);
        bool oW = (ob > best[rt][r]) || (ob == best[rt][r] && oi < bi[rt][r]);
        float nb = oW ? ob : best[rt][r];
        int ni = oW ? oi : bi[rt][r];
        float lb = oW ? best[rt][r] : ob;
        int li = oW ? bi[rt][r] : oi;
        float ws = oW ? os : secd[rt][r];
        int wi = oW ? oj : si[rt][r];
        bool sW = (ws > lb) || (ws == lb && wi < li);
        best[rt][r] = nb; bi[rt][r] = ni;
        secd[rt][r] = sW ? ws : lb; si[rt][r] = sW ? wi : li;
      }
  }
  if (col == 0) {
#pragma unroll
    for (int rt = 0; rt < 2; ++rt)
#pragma unroll
      for (int r = 0; r < 4; ++r) {
        int token = n0 + w * 32 + rt * 16 + quad * 4 + r;
        cidx[(size_t)(2 * kh + 0) * NN + token] = bi[rt][r];
        cidx[(size_t)(2 * kh + 1) * NN + token] = si[rt][r];
      }
  }
}

// == kernel 4: fused fp64 select (4 cands) + gather q + losses + conv_out ==
__global__ __launch_bounds__(256, 3) void vq_finish(
    const float* __restrict__ cb, const float* __restrict__ w_out,
    const float* __restrict__ b_out, const int* __restrict__ cidx,
    float* __restrict__ dout, float* __restrict__ loss_acc) {
  __shared__ float qs[CC][BM];
  __shared__ float xs[CC][BM];
  __shared__ float wt[CC][CC];
  __shared__ int ids[BM];
  int t = threadIdx.x;
  int n0 = blockIdx.x * BM;
  int b = n0 >> 14, s0 = n0 & (SS - 1);
  float* zreg = dout + (size_t)NN * CC;
  {  // stage wt transposed
    int o = t >> 2, c0 = (t & 3) * 16;
    const float4* wr = (const float4*)(w_out + o * CC + c0);
#pragma unroll
    for (int i = 0; i < 4; ++i) {
      float4 v = wr[i];
      int ci = c0 + 4 * i;
      wt[ci + 0][o] = v.x; wt[ci + 1][o] = v.y;
      wt[ci + 2][o] = v.z; wt[ci + 3][o] = v.w;
    }
  }
#pragma unroll
  for (int i = 0; i < 4; ++i) {  // stage xs (= xf) from z region
    int e4 = t + 256 * i;
    int ci = e4 >> 4, tok4 = (e4 & 15) * 4;
    *(float4*)&xs[ci][tok4] = *(const float4*)(zreg + (size_t)b * CC * SS +
                                               (size_t)ci * SS + s0 + tok4);
  }
  __syncthreads();
  {  // fused exact fp64 selection: 4 threads per token, lex-min (d, k)
    int tok = t >> 2, cand = t & 3;
    int kj = cidx[(size_t)cand * NN + n0 + tok];
    const float* cp = cb + (size_t)kj * CC;
    double dj = 0.0;
#pragma unroll 8
    for (int c = 0; c < CC; ++c) {
      double df = (double)xs[c][tok] - (double)cp[c];
      dj = fma(df, df, dj);
    }
#pragma unroll
    for (int step = 1; step <= 2; step <<= 1) {
      double od = __shfl_xor(dj, step, 64);
      int ok = __shfl_xor(kj, step, 64);
      if (od < dj || (od == dj && ok < kj)) { dj = od; kj = ok; }
    }
    if (cand == 0) ids[tok] = kj;
  }
  __syncthreads();
  {  // stage qs[ch][tok] = codebook[ids[tok]]
    int tok = t >> 2, c0 = (t & 3) * 16;
    const float4* qr = (const float4*)(cb + (size_t)ids[tok] * CC + c0);
#pragma unroll
    for (int i = 0; i < 4; ++i) {
      float4 v = qr[i];
      int ch = c0 + 4 * i;
      qs[ch + 0][tok] = v.x; qs[ch + 1][tok] = v.y;
      qs[ch + 2][tok] = v.z; qs[ch + 3][tok] = v.w;
    }
  }
  __syncthreads();
  float lsum = 0.f;
#pragma unroll
  for (int i = 0; i < 4; ++i) {  // losses + z := q
    int e4 = t + 256 * i;
    int ci = e4 >> 4, tok4 = (e4 & 15) * 4;
    float4 qv = *(const float4*)&qs[ci][tok4];
    float4 xv = *(const float4*)&xs[ci][tok4];
    float dx = qv.x - xv.x, dy = qv.y - xv.y;
    float dz = qv.z - xv.z, dw = qv.w - xv.w;
    lsum = fmaf(dx, dx, lsum); lsum = fmaf(dy, dy, lsum);
    lsum = fmaf(dz, dz, lsum); lsum = fmaf(dw, dw, lsum);
    *(float4*)(zreg + (size_t)b * CC * SS + (size_t)ci * SS + s0 + tok4) = qv;
  }
  int tx = t & 15, ty = t >> 4;
  float acc[4][4];
#pragma unroll
  for (int j = 0; j < 4; ++j) {
    float bj = b_out[tx * 4 + j];
#pragma unroll
    for (int m = 0; m < 4; ++m) acc[m][j] = bj;
  }
#pragma unroll 8
  for (int ci = 0; ci < CC; ++ci) {
    float4 xq = *(const float4*)&qs[ci][ty * 4];
    float4 wq = *(const float4*)&wt[ci][tx * 4];
    float xm[4] = {xq.x, xq.y, xq.z, xq.w};
    float wm[4] = {wq.x, wq.y, wq.z, wq.w};
#pragma unroll
    for (int m = 0; m < 4; ++m)
#pragma unroll
      for (int j = 0; j < 4; ++j) acc[m][j] = fmaf(xm[m], wm[j], acc[m][j]);
  }
#pragma unroll
  for (int j = 0; j < 4; ++j) {
    float4 ov = make_float4(acc[0][j], acc[1][j], acc[2][j], acc[3][j]);
    *(float4*)(dout + (size_t)b * CC * SS + (size_t)(tx * 4 + j) * SS + s0 +
               ty * 4) = ov;
  }
#pragma unroll
  for (int off = 32; off > 0; off >>= 1) lsum += __shfl_down(lsum, off, 64);
  __shared__ float wsum[4];
  if ((t & 63) == 0) wsum[t >> 6] = lsum;
  __syncthreads();
  if (t == 0) atomicAdd(loss_acc, wsum[0] + wsum[1] + wsum[2] + wsum[3]);
}

// ============ kernel 5: finalize scalar losses ============
__global__ void vq_finalize(const float* __restrict__ loss_acc,
                            float* __restrict__ dout) {
  float l = loss_acc[0] * (1.0f / (float)((size_t)NN * CC));
  dout[(size_t)2 * NN * CC + 0] = l;  // codebook_loss
  dout[(size_t)2 * NN * CC + 1] = l;  // commitment_loss
}

extern "C" void kernel_launch(void* const* d_in, const int* in_sizes, int n_in,
                              void* d_out, int out_size, void* d_ws,
                              size_t ws_size, hipStream_t stream) {
  const float* x = (const float*)d_in[0];
  const float* cb = (const float*)d_in[1];
  const float* w_in = (const float*)d_in[2];
  const float* b_in = (const float*)d_in[3];
  const float* w_out = (const float*)d_in[4];
  const float* b_out = (const float*)d_in[5];
  float* out = (float*)d_out;
  float* zreg = out + (size_t)NN * CC;  // z region doubles as xf scratch

  // ws: [0,4) loss; [1024,9216) ch; [16K,272K) cbh; [272K,528K) cbl;
  //     [528K,1552K) cidx (4 planes x NN). ~1.6 MB total.
  float* loss_acc = (float*)d_ws;
  float* ch = (float*)((char*)d_ws + 1024);
  unsigned short* cbh = (unsigned short*)((char*)d_ws + 16384);
  unsigned short* cbl = (unsigned short*)((char*)d_ws + 16384 + 262144);
  int* cidx = (int*)((char*)d_ws + 16384 + 2 * 262144);

  hipMemsetAsync(d_ws, 0, 4, stream);

  vq_conv_in<<<NN / BM, 256, 0, stream>>>(x, w_in, b_in, zreg);
  vq_split<<<KK / 256, 256, 0, stream>>>(cb, cbh, cbl, ch);
  vq_mfma_argmin<<<(NN / BMA) * 2, 256, 0, stream>>>(
      zreg, (const unsigned char*)cbh, (const unsigned char*)cbl, ch, cidx);
  vq_finish<<<NN / BM, 256, 0, stream>>>(cb, w_out, b_out, cidx, out,
                                         loss_acc);
  vq_finalize<<<1, 1, 0, stream>>>(loss_acc, out);
}